// Round 1
// baseline (1120.035 us; speedup 1.0000x reference)
//
#include <hip/hip_runtime.h>
#include <hip/hip_bf16.h>
#include <cmath>

typedef __attribute__((ext_vector_type(8))) short s8v;   // 8 bf16 (4 VGPR) MFMA operand
typedef __attribute__((ext_vector_type(4))) float f4v;   // MFMA accumulator

__device__ __forceinline__ f4v mf(s8v a, s8v b, f4v c) {
    return __builtin_amdgcn_mfma_f32_16x16x32_bf16(a, b, c, 0, 0, 0);
}

// RNE float -> bf16 bits (finite inputs only)
__device__ __forceinline__ short bf16_of(float f) {
    unsigned u = __builtin_bit_cast(unsigned, f);
    unsigned r = (u + 0x7FFFu + ((u >> 16) & 1u)) >> 16;
    return (short)r;
}
__device__ __forceinline__ float f_of_bf16(short h) {
    return __builtin_bit_cast(float, ((unsigned)(unsigned short)h) << 16);
}
__device__ __forceinline__ void split2(float v, short& h, short& l) {
    short hh = bf16_of(v);
    h = hh;
    l = bf16_of(v - f_of_bf16(hh));
}

#define SB 2048      // sequence length
#define DD 1024      // model dim
#define NH 16        // heads
#define MTOT 4096    // B*S rows

// ---------------------------------------------------------------------------
// GEMM1: [4096 x 2048] x [2048 x 6144] with 3-pass bf16 split.
// A = [z_real | z_imag]; B packed per complex linear; epilogue -> QK hi/lo + V^T
// ---------------------------------------------------------------------------
__global__ __launch_bounds__(256) void gemm_qkv(
    const float* __restrict__ zr, const float* __restrict__ zi,
    const float* __restrict__ qwr, const float* __restrict__ qwi,
    const float* __restrict__ kwr, const float* __restrict__ kwi,
    const float* __restrict__ vwr, const float* __restrict__ vwi,
    short* __restrict__ QKhi, short* __restrict__ QKlo,
    short* __restrict__ Vtr, short* __restrict__ Vti)
{
    __shared__ short Ah[128][40], Al[128][40], Bh[128][40], Bl[128][40];
    const int tid = threadIdx.x;
    const int lane = tid & 63, wid = tid >> 6;
    const int c = lane & 15, g = lane >> 4;
    const int wr = wid >> 1, wc = wid & 1;
    const int nt = blockIdx.x, mt = blockIdx.y;
    const int m0 = mt * 128, n0 = nt * 128;

    const int t = n0 >> 11;                       // 0=q 1=k 2=v
    const float* Wr = (t == 0) ? qwr : (t == 1) ? kwr : vwr;
    const float* Wi = (t == 0) ? qwi : (t == 1) ? kwi : vwi;
    const int cpart = (n0 >> 10) & 1;             // 0=real-out 1=imag-out
    const int obase = n0 & 1023;

    const f4v zero4 = {0.f, 0.f, 0.f, 0.f};
    f4v acc[4][4];
#pragma unroll
    for (int mi = 0; mi < 4; ++mi)
#pragma unroll
        for (int ni = 0; ni < 4; ++ni) acc[mi][ni] = zero4;

    const int srow = tid >> 3;          // 0..31
    const int sk = (tid & 7) * 4;       // 0..28

    for (int kt = 0; kt < 64; ++kt) {
        const int k0 = kt * 32;
        const int kk0 = k0 & 1023;
        const bool khalf = (k0 >= 1024);
        const float* zsrc = khalf ? zi : zr;
        const float* Wsrc;
        float sgn;
        if (!khalf) { Wsrc = cpart ? Wi : Wr; sgn = 1.f; }
        else        { Wsrc = cpart ? Wr : Wi; sgn = cpart ? 1.f : -1.f; }

        __syncthreads();
#pragma unroll
        for (int it = 0; it < 4; ++it) {
            int r = srow + it * 32;
            float4 va = *reinterpret_cast<const float4*>(zsrc + (m0 + r) * 1024 + kk0 + sk);
#pragma unroll
            for (int e = 0; e < 4; ++e)
                split2((&va.x)[e], Ah[r][sk + e], Al[r][sk + e]);
            float4 vb = *reinterpret_cast<const float4*>(Wsrc + (obase + r) * 1024 + kk0 + sk);
#pragma unroll
            for (int e = 0; e < 4; ++e)
                split2(sgn * (&vb.x)[e], Bh[r][sk + e], Bl[r][sk + e]);
        }
        __syncthreads();

        s8v ah[4], alo[4], bh[4], blo[4];
#pragma unroll
        for (int i = 0; i < 4; ++i) {
            ah[i]  = *reinterpret_cast<const s8v*>(&Ah[wr * 64 + i * 16 + c][8 * g]);
            alo[i] = *reinterpret_cast<const s8v*>(&Al[wr * 64 + i * 16 + c][8 * g]);
            bh[i]  = *reinterpret_cast<const s8v*>(&Bh[wc * 64 + i * 16 + c][8 * g]);
            blo[i] = *reinterpret_cast<const s8v*>(&Bl[wc * 64 + i * 16 + c][8 * g]);
        }
#pragma unroll
        for (int mi = 0; mi < 4; ++mi)
#pragma unroll
            for (int ni = 0; ni < 4; ++ni) {
                acc[mi][ni] = mf(ah[mi], bh[ni], acc[mi][ni]);
                acc[mi][ni] = mf(ah[mi], blo[ni], acc[mi][ni]);
                acc[mi][ni] = mf(alo[mi], bh[ni], acc[mi][ni]);
            }
    }

    // epilogue
#pragma unroll
    for (int mi = 0; mi < 4; ++mi) {
#pragma unroll
        for (int ni = 0; ni < 4; ++ni) {
            int col = n0 + wc * 64 + ni * 16 + c;
            int rbase = m0 + wr * 64 + mi * 16 + 4 * g;
            if (col < 4096) {
#pragma unroll
                for (int j = 0; j < 4; ++j) {
                    short h, l;
                    split2(acc[mi][ni][j], h, l);
                    QKhi[(rbase + j) * 4096 + col] = h;
                    QKlo[(rbase + j) * 4096 + col] = l;
                }
            } else {
                int cc = col - 4096;
                int part = cc >> 10, o = cc & 1023;
                int hh = o >> 6, d = o & 63;
                int bb = rbase >> 11, s = rbase & 2047;
                short* vt = part ? Vti : Vtr;
                ushort4 pk;
                pk.x = (unsigned short)bf16_of(acc[mi][ni][0]);
                pk.y = (unsigned short)bf16_of(acc[mi][ni][1]);
                pk.z = (unsigned short)bf16_of(acc[mi][ni][2]);
                pk.w = (unsigned short)bf16_of(acc[mi][ni][3]);
                *reinterpret_cast<ushort4*>(&vt[((bb * 16 + hh) * 64 + d) * 2048 + s]) = pk;
            }
        }
    }
}

// ---------------------------------------------------------------------------
// Fused flash attention. 4 waves/block, 16 queries/wave, 64-key tiles.
// ---------------------------------------------------------------------------
__global__ __launch_bounds__(256) void attn_fused(
    const short* __restrict__ QKhi, const short* __restrict__ QKlo,
    const short* __restrict__ Vtr, const short* __restrict__ Vti,
    short* __restrict__ aout)
{
    __shared__ short p_lds[4][16][72];
    const int tid = threadIdx.x, lane = tid & 63, wid = tid >> 6;
    const int c = lane & 15, g = lane >> 4;
    const int qt = blockIdx.x, h = blockIdx.y, b = blockIdx.z;
    const int q0 = qt * 64 + wid * 16;
    const int mq = b * 2048 + q0 + c;

    s8v qrh[2], qrl[2], qih[2], qil[2], nqrh[2], nqrl[2];
#pragma unroll
    for (int ks = 0; ks < 2; ++ks) {
        int colr = h * 64 + ks * 32 + 8 * g;
        qrh[ks] = *reinterpret_cast<const s8v*>(&QKhi[mq * 4096 + colr]);
        qrl[ks] = *reinterpret_cast<const s8v*>(&QKlo[mq * 4096 + colr]);
        qih[ks] = *reinterpret_cast<const s8v*>(&QKhi[mq * 4096 + 1024 + colr]);
        qil[ks] = *reinterpret_cast<const s8v*>(&QKlo[mq * 4096 + 1024 + colr]);
        nqrh[ks] = qrh[ks] ^ (short)0x8000;
        nqrl[ks] = qrl[ks] ^ (short)0x8000;
    }

    const f4v zero4 = {0.f, 0.f, 0.f, 0.f};
    f4v aor[4], aoi[4];
#pragma unroll
    for (int dt = 0; dt < 4; ++dt) { aor[dt] = zero4; aoi[dt] = zero4; }
    float mrun[4], lrun[4];
#pragma unroll
    for (int j = 0; j < 4; ++j) { mrun[j] = -INFINITY; lrun[j] = 0.f; }

    for (int kt = 0; kt < 32; ++kt) {
        f4v sv[4];
#pragma unroll
        for (int kn = 0; kn < 4; ++kn) {
            f4v sr = zero4, si = zero4;
            int rowk = (b * 2048 + kt * 64 + kn * 16 + c) * 4096 + 2048 + h * 64;
#pragma unroll
            for (int ks = 0; ks < 2; ++ks) {
                int off = rowk + ks * 32 + 8 * g;
                s8v krh = *reinterpret_cast<const s8v*>(&QKhi[off]);
                s8v krl = *reinterpret_cast<const s8v*>(&QKlo[off]);
                s8v kih = *reinterpret_cast<const s8v*>(&QKhi[off + 1024]);
                s8v kil = *reinterpret_cast<const s8v*>(&QKlo[off + 1024]);
                sr = mf(qrh[ks], krh, sr); sr = mf(qrh[ks], krl, sr); sr = mf(qrl[ks], krh, sr);
                sr = mf(qih[ks], kih, sr); sr = mf(qih[ks], kil, sr); sr = mf(qil[ks], kih, sr);
                si = mf(qih[ks], krh, si); si = mf(qih[ks], krl, si); si = mf(qil[ks], krh, si);
                si = mf(nqrh[ks], kih, si); si = mf(nqrh[ks], kil, si); si = mf(nqrl[ks], kih, si);
            }
#pragma unroll
            for (int j = 0; j < 4; ++j) {
                float a = fminf(fmaxf(sr[j], -250.f), 250.f);
                float bb2 = fminf(fmaxf(si[j], -250.f), 250.f);
                sv[kn][j] = sqrtf(a * a + bb2 * bb2) * 0.125f;
            }
        }
        float cf[4], rs[4];
#pragma unroll
        for (int j = 0; j < 4; ++j) {
            float tm = fmaxf(fmaxf(sv[0][j], sv[1][j]), fmaxf(sv[2][j], sv[3][j]));
#pragma unroll
            for (int off = 1; off < 16; off <<= 1) tm = fmaxf(tm, __shfl_xor(tm, off));
            float mn = fmaxf(mrun[j], tm);
            cf[j] = __expf(mrun[j] - mn);
            mrun[j] = mn;
            rs[j] = 0.f;
        }
#pragma unroll
        for (int kn = 0; kn < 4; ++kn)
#pragma unroll
            for (int j = 0; j < 4; ++j) {
                float p = __expf(sv[kn][j] - mrun[j]);
                sv[kn][j] = p;
                rs[j] += p;
            }
#pragma unroll
        for (int j = 0; j < 4; ++j) {
            float r = rs[j];
#pragma unroll
            for (int off = 1; off < 16; off <<= 1) r += __shfl_xor(r, off);
            lrun[j] = lrun[j] * cf[j] + r;
        }
        f4v cfv = {cf[0], cf[1], cf[2], cf[3]};
#pragma unroll
        for (int dt = 0; dt < 4; ++dt) { aor[dt] *= cfv; aoi[dt] *= cfv; }

#pragma unroll
        for (int kn = 0; kn < 4; ++kn)
#pragma unroll
            for (int j = 0; j < 4; ++j)
                p_lds[wid][4 * g + j][kn * 16 + c] = bf16_of(sv[kn][j]);
        asm volatile("s_waitcnt lgkmcnt(0)" ::: "memory");
        __builtin_amdgcn_sched_barrier(0);

        int vbase = ((b * 16 + h) * 64) * 2048 + kt * 64;
#pragma unroll
        for (int ks = 0; ks < 2; ++ks) {
            s8v pa = *reinterpret_cast<const s8v*>(&p_lds[wid][c][ks * 32 + 8 * g]);
#pragma unroll
            for (int dt = 0; dt < 4; ++dt) {
                int va = vbase + (dt * 16 + c) * 2048 + ks * 32 + 8 * g;
                s8v vr = *reinterpret_cast<const s8v*>(&Vtr[va]);
                s8v vi = *reinterpret_cast<const s8v*>(&Vti[va]);
                aor[dt] = mf(pa, vr, aor[dt]);
                aoi[dt] = mf(pa, vi, aoi[dt]);
            }
        }
    }

    f4v ilv;
#pragma unroll
    for (int j = 0; j < 4; ++j) ilv[j] = 1.f / lrun[j];
#pragma unroll
    for (int dt = 0; dt < 4; ++dt) {
        f4v orv = aor[dt] * ilv, oiv = aoi[dt] * ilv;
#pragma unroll
        for (int j = 0; j < 4; ++j) {
            int row = b * 2048 + q0 + 4 * g + j;
            aout[row * 2048 + h * 64 + dt * 16 + c] = bf16_of(orv[j]);
            aout[row * 2048 + 1024 + h * 64 + dt * 16 + c] = bf16_of(oiv[j]);
        }
    }
}

// ---------------------------------------------------------------------------
// GEMM2: attn_out [4096 x 2048] x packed o_w [2048 x 2048] -> yr|yi fp32
// ---------------------------------------------------------------------------
__global__ __launch_bounds__(256) void gemm_out(
    const short* __restrict__ A,
    const float* __restrict__ owr, const float* __restrict__ owi,
    float* __restrict__ out)
{
    __shared__ short Ah[128][40], Bh[128][40];
    const int tid = threadIdx.x;
    const int lane = tid & 63, wid = tid >> 6;
    const int c = lane & 15, g = lane >> 4;
    const int wr = wid >> 1, wc = wid & 1;
    const int nt = blockIdx.x, mt = blockIdx.y;
    const int m0 = mt * 128, n0 = nt * 128;
    const int part = n0 >> 10;
    const int obase = n0 & 1023;

    const f4v zero4 = {0.f, 0.f, 0.f, 0.f};
    f4v acc[4][4];
#pragma unroll
    for (int mi = 0; mi < 4; ++mi)
#pragma unroll
        for (int ni = 0; ni < 4; ++ni) acc[mi][ni] = zero4;

    const int srow = tid >> 3;
    const int sk = (tid & 7) * 4;

    for (int kt = 0; kt < 64; ++kt) {
        const int k0 = kt * 32;
        const int kk0 = k0 & 1023;
        const bool khalf = (k0 >= 1024);
        const float* Wsrc = !khalf ? (part ? owi : owr) : (part ? owr : owi);
        const float sgn = (khalf && !part) ? -1.f : 1.f;

        __syncthreads();
#pragma unroll
        for (int it = 0; it < 4; ++it) {
            int r = srow + it * 32;
            *reinterpret_cast<uint2*>(&Ah[r][sk]) =
                *reinterpret_cast<const uint2*>(&A[(m0 + r) * 2048 + k0 + sk]);
            float4 vb = *reinterpret_cast<const float4*>(Wsrc + (obase + r) * 1024 + kk0 + sk);
#pragma unroll
            for (int e = 0; e < 4; ++e)
                Bh[r][sk + e] = bf16_of(sgn * (&vb.x)[e]);
        }
        __syncthreads();

        s8v af[4], bf[4];
#pragma unroll
        for (int i = 0; i < 4; ++i) {
            af[i] = *reinterpret_cast<const s8v*>(&Ah[wr * 64 + i * 16 + c][8 * g]);
            bf[i] = *reinterpret_cast<const s8v*>(&Bh[wc * 64 + i * 16 + c][8 * g]);
        }
#pragma unroll
        for (int mi = 0; mi < 4; ++mi)
#pragma unroll
            for (int ni = 0; ni < 4; ++ni)
                acc[mi][ni] = mf(af[mi], bf[ni], acc[mi][ni]);
    }

#pragma unroll
    for (int mi = 0; mi < 4; ++mi)
#pragma unroll
        for (int ni = 0; ni < 4; ++ni) {
            int col = n0 + wc * 64 + ni * 16 + c;
#pragma unroll
            for (int j = 0; j < 4; ++j) {
                int row = m0 + wr * 64 + mi * 16 + 4 * g + j;
                float v = acc[mi][ni][j];
                if (col < 1024) out[row * 1024 + col] = v;
                else out[4194304 + row * 1024 + (col - 1024)] = v;
            }
        }
}

extern "C" void kernel_launch(void* const* d_in, const int* in_sizes, int n_in,
                              void* d_out, int out_size, void* d_ws, size_t ws_size,
                              hipStream_t stream) {
    const float* zr  = (const float*)d_in[0];
    const float* zi  = (const float*)d_in[1];
    const float* qwr = (const float*)d_in[2];
    const float* qwi = (const float*)d_in[3];
    const float* kwr = (const float*)d_in[4];
    const float* kwi = (const float*)d_in[5];
    const float* vwr = (const float*)d_in[6];
    const float* vwi = (const float*)d_in[7];
    const float* owr = (const float*)d_in[8];
    const float* owi = (const float*)d_in[9];

    char* ws = (char*)d_ws;
    short* QKhi = (short*)(ws);                     // 4096*4096*2 = 33554432 B
    short* QKlo = (short*)(ws + 33554432);          // 33554432 B
    short* Vtr  = (short*)(ws + 67108864);          // 8388608 B
    short* Vti  = (short*)(ws + 75497472);          // 8388608 B
    short* aout = (short*)(ws + 83886080);          // 16777216 B  (total ~100 MB)

    gemm_qkv<<<dim3(48, 32, 1), 256, 0, stream>>>(zr, zi, qwr, qwi, kwr, kwi, vwr, vwi,
                                                  QKhi, QKlo, Vtr, Vti);
    attn_fused<<<dim3(32, 16, 2), 256, 0, stream>>>(QKhi, QKlo, Vtr, Vti, aout);
    gemm_out<<<dim3(16, 32, 1), 256, 0, stream>>>(aout, owr, owi, (float*)d_out);
}

// Round 2
// 806.626 us; speedup vs baseline: 1.3885x; 1.3885x over previous
//
#include <hip/hip_runtime.h>
#include <hip/hip_bf16.h>
#include <cmath>

typedef __attribute__((ext_vector_type(8))) short s8v;   // 8 bf16 (4 VGPR) MFMA operand
typedef __attribute__((ext_vector_type(4))) float f4v;   // MFMA accumulator

__device__ __forceinline__ f4v mf(s8v a, s8v b, f4v c) {
    return __builtin_amdgcn_mfma_f32_16x16x32_bf16(a, b, c, 0, 0, 0);
}

// RNE float -> bf16 bits (finite inputs only)
__device__ __forceinline__ short bf16_of(float f) {
    unsigned u = __builtin_bit_cast(unsigned, f);
    unsigned r = (u + 0x7FFFu + ((u >> 16) & 1u)) >> 16;
    return (short)r;
}
__device__ __forceinline__ float f_of_bf16(short h) {
    return __builtin_bit_cast(float, ((unsigned)(unsigned short)h) << 16);
}
__device__ __forceinline__ void split2(float v, short& h, short& l) {
    short hh = bf16_of(v);
    h = hh;
    l = bf16_of(v - f_of_bf16(hh));
}

// ---------------------------------------------------------------------------
// GEMM1: [4096 x 2048] x [2048 x 6144] with 3-pass bf16 split.
// A = [z_real | z_imag]; B packed per complex linear; epilogue -> QK hi/lo + V^T
// ---------------------------------------------------------------------------
__global__ __launch_bounds__(256) void gemm_qkv(
    const float* __restrict__ zr, const float* __restrict__ zi,
    const float* __restrict__ qwr, const float* __restrict__ qwi,
    const float* __restrict__ kwr, const float* __restrict__ kwi,
    const float* __restrict__ vwr, const float* __restrict__ vwi,
    short* __restrict__ QKhi, short* __restrict__ QKlo,
    short* __restrict__ Vtr, short* __restrict__ Vti)
{
    __shared__ short Ah[128][40], Al[128][40], Bh[128][40], Bl[128][40];
    const int tid = threadIdx.x;
    const int lane = tid & 63, wid = tid >> 6;
    const int c = lane & 15, g = lane >> 4;
    const int wr = wid >> 1, wc = wid & 1;
    const int nt = blockIdx.x, mt = blockIdx.y;
    const int m0 = mt * 128, n0 = nt * 128;

    const int t = n0 >> 11;                       // 0=q 1=k 2=v
    const float* Wr = (t == 0) ? qwr : (t == 1) ? kwr : vwr;
    const float* Wi = (t == 0) ? qwi : (t == 1) ? kwi : vwi;
    const int cpart = (n0 >> 10) & 1;             // 0=real-out 1=imag-out
    const int obase = n0 & 1023;

    const f4v zero4 = {0.f, 0.f, 0.f, 0.f};
    f4v acc[4][4];
#pragma unroll
    for (int mi = 0; mi < 4; ++mi)
#pragma unroll
        for (int ni = 0; ni < 4; ++ni) acc[mi][ni] = zero4;

    const int srow = tid >> 3;          // 0..31
    const int sk = (tid & 7) * 4;       // 0..28

    for (int kt = 0; kt < 64; ++kt) {
        const int k0 = kt * 32;
        const int kk0 = k0 & 1023;
        const bool khalf = (k0 >= 1024);
        const float* zsrc = khalf ? zi : zr;
        const float* Wsrc;
        float sgn;
        if (!khalf) { Wsrc = cpart ? Wi : Wr; sgn = 1.f; }
        else        { Wsrc = cpart ? Wr : Wi; sgn = cpart ? 1.f : -1.f; }

        __syncthreads();
#pragma unroll
        for (int it = 0; it < 4; ++it) {
            int r = srow + it * 32;
            float4 va = *reinterpret_cast<const float4*>(zsrc + (m0 + r) * 1024 + kk0 + sk);
#pragma unroll
            for (int e = 0; e < 4; ++e)
                split2((&va.x)[e], Ah[r][sk + e], Al[r][sk + e]);
            float4 vb = *reinterpret_cast<const float4*>(Wsrc + (obase + r) * 1024 + kk0 + sk);
#pragma unroll
            for (int e = 0; e < 4; ++e)
                split2(sgn * (&vb.x)[e], Bh[r][sk + e], Bl[r][sk + e]);
        }
        __syncthreads();

        s8v ah[4], alo[4], bh[4], blo[4];
#pragma unroll
        for (int i = 0; i < 4; ++i) {
            ah[i]  = *reinterpret_cast<const s8v*>(&Ah[wr * 64 + i * 16 + c][8 * g]);
            alo[i] = *reinterpret_cast<const s8v*>(&Al[wr * 64 + i * 16 + c][8 * g]);
            bh[i]  = *reinterpret_cast<const s8v*>(&Bh[wc * 64 + i * 16 + c][8 * g]);
            blo[i] = *reinterpret_cast<const s8v*>(&Bl[wc * 64 + i * 16 + c][8 * g]);
        }
#pragma unroll
        for (int mi = 0; mi < 4; ++mi)
#pragma unroll
            for (int ni = 0; ni < 4; ++ni) {
                acc[mi][ni] = mf(ah[mi], bh[ni], acc[mi][ni]);
                acc[mi][ni] = mf(ah[mi], blo[ni], acc[mi][ni]);
                acc[mi][ni] = mf(alo[mi], bh[ni], acc[mi][ni]);
            }
    }

    // epilogue
#pragma unroll
    for (int mi = 0; mi < 4; ++mi) {
#pragma unroll
        for (int ni = 0; ni < 4; ++ni) {
            int col = n0 + wc * 64 + ni * 16 + c;
            int rbase = m0 + wr * 64 + mi * 16 + 4 * g;
            if (col < 4096) {
#pragma unroll
                for (int j = 0; j < 4; ++j) {
                    short h, l;
                    split2(acc[mi][ni][j], h, l);
                    QKhi[(rbase + j) * 4096 + col] = h;
                    if (col < 2048) QKlo[(rbase + j) * 4096 + col] = l;  // K-lo never read
                }
            } else {
                int cc = col - 4096;
                int part = cc >> 10, o = cc & 1023;
                int hh = o >> 6, d = o & 63;
                int bb = rbase >> 11, s = rbase & 2047;
                short* vt = part ? Vti : Vtr;
                ushort4 pk;
                pk.x = (unsigned short)bf16_of(acc[mi][ni][0]);
                pk.y = (unsigned short)bf16_of(acc[mi][ni][1]);
                pk.z = (unsigned short)bf16_of(acc[mi][ni][2]);
                pk.w = (unsigned short)bf16_of(acc[mi][ni][3]);
                *reinterpret_cast<ushort4*>(&vt[((bb * 16 + hh) * 64 + d) * 2048 + s]) = pk;
            }
        }
    }
}

// ---------------------------------------------------------------------------
// Fused flash attention. 4 waves/block, 16 queries/wave, 64-key tiles.
// K (hi only) staged in LDS shared across waves, double-buffered, XOR-swizzled.
// XCD-aware swizzle keeps all q-tiles of one (b,h) on one XCD for L2 locality.
// ---------------------------------------------------------------------------
__global__ __launch_bounds__(256) void attn_fused(
    const short* __restrict__ QKhi, const short* __restrict__ QKlo,
    const short* __restrict__ Vtr, const short* __restrict__ Vti,
    short* __restrict__ aout)
{
    __shared__ short kbuf[2][64][128];      // 32 KB: rows=key, 16 slots of 16B (kr|ki), XOR-swizzled
    __shared__ short p_lds[4][16][64];      // 8 KB per-wave P tile, XOR-swizzled
    const int tid = threadIdx.x, lane = tid & 63, wid = tid >> 6;
    const int c = lane & 15, g = lane >> 4;

    // XCD swizzle: blocks 0..1023, consecutive ids round-robin XCDs ->
    // give each XCD whole (b,h) groups (32 qt blocks each).
    const int L = blockIdx.x;
    const int idx = L >> 3;
    const int p = (L & 7) + ((idx >> 5) << 3);   // (b,h) pair 0..31
    const int qt = idx & 31;
    const int h = p & 15, b = p >> 4;

    const int q0 = qt * 64 + wid * 16;
    const int mq = b * 2048 + q0 + c;

    // Q fragments (hi/lo, r/i) held in registers for the whole kernel
    s8v qrh[2], qrl[2], qih[2], qil[2], nqrh[2], nqrl[2];
#pragma unroll
    for (int ks = 0; ks < 2; ++ks) {
        int colr = h * 64 + ks * 32 + 8 * g;
        qrh[ks] = *reinterpret_cast<const s8v*>(&QKhi[(size_t)mq * 4096 + colr]);
        qrl[ks] = *reinterpret_cast<const s8v*>(&QKlo[(size_t)mq * 4096 + colr]);
        qih[ks] = *reinterpret_cast<const s8v*>(&QKhi[(size_t)mq * 4096 + 1024 + colr]);
        qil[ks] = *reinterpret_cast<const s8v*>(&QKlo[(size_t)mq * 4096 + 1024 + colr]);
        nqrh[ks] = qrh[ks] ^ (short)0x8000;
        nqrl[ks] = qrl[ks] ^ (short)0x8000;
    }

    // K staging geometry: LDS row r holds key (kt*64+r); slot s (16B) holds
    // content slot_u = s ^ (r&7); slot_u 0..7 = kr d[8*slot_u..], 8..15 = ki.
    const int srow = tid >> 4;                 // 0..15 (row within 16-row group)
    const int sslot = tid & 15;                // 16B slot = destination slot
    const int slot_u = sslot ^ (srow & 7);     // (i*16+srow)&7 == srow&7
    const int gcol = 2048 + (slot_u >> 3) * 1024 + h * 64 + (slot_u & 7) * 8;
    const short* gK = QKhi + (size_t)(b * 2048) * 4096 + gcol;

    const f4v zero4 = {0.f, 0.f, 0.f, 0.f};
    f4v aor[4], aoi[4];
#pragma unroll
    for (int dt = 0; dt < 4; ++dt) { aor[dt] = zero4; aoi[dt] = zero4; }
    float mrun[4], lrun[4];
#pragma unroll
    for (int j = 0; j < 4; ++j) { mrun[j] = -INFINITY; lrun[j] = 0.f; }

    // prologue: stage tile 0
#pragma unroll
    for (int i = 0; i < 4; ++i)
        __builtin_amdgcn_global_load_lds(gK + (size_t)(i * 16 + srow) * 4096,
                                         &kbuf[0][i * 16 + wid * 4][0], 16, 0, 0);
    __syncthreads();

    for (int kt = 0; kt < 32; ++kt) {
        const int buf = kt & 1;
        if (kt + 1 < 32) {
#pragma unroll
            for (int i = 0; i < 4; ++i)
                __builtin_amdgcn_global_load_lds(
                    gK + (size_t)((kt + 1) * 64 + i * 16 + srow) * 4096,
                    &kbuf[buf ^ 1][i * 16 + wid * 4][0], 16, 0, 0);
        }

        f4v sv[4];
#pragma unroll
        for (int kn = 0; kn < 4; ++kn) {
            f4v sr = zero4, si = zero4;
            const int row = kn * 16 + c;
#pragma unroll
            for (int ks = 0; ks < 2; ++ks) {
                const int sl = (((ks * 4 + g) ^ (c & 7))) * 8;
                s8v krh = *reinterpret_cast<const s8v*>(&kbuf[buf][row][sl]);
                s8v kih = *reinterpret_cast<const s8v*>(&kbuf[buf][row][sl + 64]);
                sr = mf(qrh[ks], krh, sr); sr = mf(qrl[ks], krh, sr);
                sr = mf(qih[ks], kih, sr); sr = mf(qil[ks], kih, sr);
                si = mf(qih[ks], krh, si); si = mf(qil[ks], krh, si);
                si = mf(nqrh[ks], kih, si); si = mf(nqrl[ks], kih, si);
            }
#pragma unroll
            for (int j = 0; j < 4; ++j) {
                float a = fminf(fmaxf(sr[j], -250.f), 250.f);
                float e = fminf(fmaxf(si[j], -250.f), 250.f);
                sv[kn][j] = sqrtf(a * a + e * e) * 0.125f;
            }
        }

        float cf[4], rs[4];
#pragma unroll
        for (int j = 0; j < 4; ++j) {
            float tm = fmaxf(fmaxf(sv[0][j], sv[1][j]), fmaxf(sv[2][j], sv[3][j]));
#pragma unroll
            for (int off = 1; off < 16; off <<= 1) tm = fmaxf(tm, __shfl_xor(tm, off));
            float mn = fmaxf(mrun[j], tm);
            cf[j] = __expf(mrun[j] - mn);
            mrun[j] = mn;
            rs[j] = 0.f;
        }
#pragma unroll
        for (int kn = 0; kn < 4; ++kn)
#pragma unroll
            for (int j = 0; j < 4; ++j) {
                float pv = __expf(sv[kn][j] - mrun[j]);
                sv[kn][j] = pv;
                rs[j] += pv;
            }
#pragma unroll
        for (int j = 0; j < 4; ++j) {
            float r = rs[j];
#pragma unroll
            for (int off = 1; off < 16; off <<= 1) r += __shfl_xor(r, off);
            lrun[j] = lrun[j] * cf[j] + r;
        }
        f4v cfv = {cf[0], cf[1], cf[2], cf[3]};
#pragma unroll
        for (int dt = 0; dt < 4; ++dt) { aor[dt] *= cfv; aoi[dt] *= cfv; }

        // P -> per-wave LDS (XOR-swizzled on 8-short granule), reshape to A-frag
#pragma unroll
        for (int kn = 0; kn < 4; ++kn)
#pragma unroll
            for (int j = 0; j < 4; ++j) {
                int q = 4 * g + j;
                p_lds[wid][q][(kn * 16 + c) ^ ((q & 7) << 3)] = bf16_of(sv[kn][j]);
            }
        asm volatile("s_waitcnt lgkmcnt(0)" ::: "memory");
        __builtin_amdgcn_sched_barrier(0);

        const size_t vbase = (size_t)((b * 16 + h) * 64) * 2048 + kt * 64;
#pragma unroll
        for (int ks = 0; ks < 2; ++ks) {
            s8v pa = *reinterpret_cast<const s8v*>(
                &p_lds[wid][c][(ks * 32 + 8 * g) ^ ((c & 7) << 3)]);
#pragma unroll
            for (int dt = 0; dt < 4; ++dt) {
                size_t va = vbase + (size_t)(dt * 16 + c) * 2048 + ks * 32 + 8 * g;
                s8v vr = *reinterpret_cast<const s8v*>(&Vtr[va]);
                s8v vi = *reinterpret_cast<const s8v*>(&Vti[va]);
                aor[dt] = mf(pa, vr, aor[dt]);
                aoi[dt] = mf(pa, vi, aoi[dt]);
            }
        }
        __syncthreads();   // drains vmcnt: next tile staged; kbuf[buf] free to overwrite
    }

    f4v ilv;
#pragma unroll
    for (int j = 0; j < 4; ++j) ilv[j] = 1.f / lrun[j];
#pragma unroll
    for (int dt = 0; dt < 4; ++dt) {
        f4v orv = aor[dt] * ilv, oiv = aoi[dt] * ilv;
#pragma unroll
        for (int j = 0; j < 4; ++j) {
            int row = b * 2048 + q0 + 4 * g + j;
            aout[(size_t)row * 2048 + h * 64 + dt * 16 + c] = bf16_of(orv[j]);
            aout[(size_t)row * 2048 + 1024 + h * 64 + dt * 16 + c] = bf16_of(oiv[j]);
        }
    }
}

// ---------------------------------------------------------------------------
// GEMM2: attn_out [4096 x 2048] x packed o_w [2048 x 2048] -> yr|yi fp32
// ---------------------------------------------------------------------------
__global__ __launch_bounds__(256) void gemm_out(
    const short* __restrict__ A,
    const float* __restrict__ owr, const float* __restrict__ owi,
    float* __restrict__ out)
{
    __shared__ short Ah[128][40], Bh[128][40];
    const int tid = threadIdx.x;
    const int lane = tid & 63, wid = tid >> 6;
    const int c = lane & 15, g = lane >> 4;
    const int wr = wid >> 1, wc = wid & 1;
    const int nt = blockIdx.x, mt = blockIdx.y;
    const int m0 = mt * 128, n0 = nt * 128;
    const int part = n0 >> 10;
    const int obase = n0 & 1023;

    const f4v zero4 = {0.f, 0.f, 0.f, 0.f};
    f4v acc[4][4];
#pragma unroll
    for (int mi = 0; mi < 4; ++mi)
#pragma unroll
        for (int ni = 0; ni < 4; ++ni) acc[mi][ni] = zero4;

    const int srow = tid >> 3;
    const int sk = (tid & 7) * 4;

    for (int kt = 0; kt < 64; ++kt) {
        const int k0 = kt * 32;
        const int kk0 = k0 & 1023;
        const bool khalf = (k0 >= 1024);
        const float* Wsrc = !khalf ? (part ? owi : owr) : (part ? owr : owi);
        const float sgn = (khalf && !part) ? -1.f : 1.f;

        __syncthreads();
#pragma unroll
        for (int it = 0; it < 4; ++it) {
            int r = srow + it * 32;
            *reinterpret_cast<uint2*>(&Ah[r][sk]) =
                *reinterpret_cast<const uint2*>(&A[(m0 + r) * 2048 + k0 + sk]);
            float4 vb = *reinterpret_cast<const float4*>(Wsrc + (obase + r) * 1024 + kk0 + sk);
#pragma unroll
            for (int e = 0; e < 4; ++e)
                Bh[r][sk + e] = bf16_of(sgn * (&vb.x)[e]);
        }
        __syncthreads();

        s8v af[4], bf[4];
#pragma unroll
        for (int i = 0; i < 4; ++i) {
            af[i] = *reinterpret_cast<const s8v*>(&Ah[wr * 64 + i * 16 + c][8 * g]);
            bf[i] = *reinterpret_cast<const s8v*>(&Bh[wc * 64 + i * 16 + c][8 * g]);
        }
#pragma unroll
        for (int mi = 0; mi < 4; ++mi)
#pragma unroll
            for (int ni = 0; ni < 4; ++ni)
                acc[mi][ni] = mf(af[mi], bf[ni], acc[mi][ni]);
    }

#pragma unroll
    for (int mi = 0; mi < 4; ++mi)
#pragma unroll
        for (int ni = 0; ni < 4; ++ni) {
            int col = n0 + wc * 64 + ni * 16 + c;
#pragma unroll
            for (int j = 0; j < 4; ++j) {
                int row = m0 + wr * 64 + mi * 16 + 4 * g + j;
                float v = acc[mi][ni][j];
                if (col < 1024) out[row * 1024 + col] = v;
                else out[4194304 + row * 1024 + (col - 1024)] = v;
            }
        }
}

extern "C" void kernel_launch(void* const* d_in, const int* in_sizes, int n_in,
                              void* d_out, int out_size, void* d_ws, size_t ws_size,
                              hipStream_t stream) {
    const float* zr  = (const float*)d_in[0];
    const float* zi  = (const float*)d_in[1];
    const float* qwr = (const float*)d_in[2];
    const float* qwi = (const float*)d_in[3];
    const float* kwr = (const float*)d_in[4];
    const float* kwi = (const float*)d_in[5];
    const float* vwr = (const float*)d_in[6];
    const float* vwi = (const float*)d_in[7];
    const float* owr = (const float*)d_in[8];
    const float* owi = (const float*)d_in[9];

    char* ws = (char*)d_ws;
    short* QKhi = (short*)(ws);                     // 33554432 B
    short* QKlo = (short*)(ws + 33554432);          // 33554432 B
    short* Vtr  = (short*)(ws + 67108864);          // 8388608 B
    short* Vti  = (short*)(ws + 75497472);          // 8388608 B
    short* aout = (short*)(ws + 83886080);          // 16777216 B

    gemm_qkv<<<dim3(48, 32, 1), 256, 0, stream>>>(zr, zi, qwr, qwi, kwr, kwi, vwr, vwi,
                                                  QKhi, QKlo, Vtr, Vti);
    attn_fused<<<dim3(1024, 1, 1), 256, 0, stream>>>(QKhi, QKlo, Vtr, Vti, aout);
    gemm_out<<<dim3(16, 32, 1), 256, 0, stream>>>(aout, owr, owi, (float*)d_out);
}